// Round 1
// 667.893 us; speedup vs baseline: 1.0114x; 1.0114x over previous
//
#include <hip/hip_runtime.h>
#include <stdint.h>

// ---- problem constants ----
#define ATTN_S  2048
#define ATTN_D  64
#define ATTN_BH 32           // B*H = 2*16
#define QT      128          // q rows per block
#define KT      64           // k cols per tile iteration
#define NT      (ATTN_S / KT)  // 32 tiles
#define NWAVE   8            // 512 threads
#define LOG2E   1.4426950408889634f

typedef _Float16 half8   __attribute__((ext_vector_type(8)));
typedef _Float16 half4v  __attribute__((ext_vector_type(4)));
typedef float    floatx4 __attribute__((ext_vector_type(4)));

// workspace: [Qh 8MB][Kh 8MB (chunk-swizzled)][Vt 8MB (tiled+swizzled)]
#define QH_ELEMS ((size_t)ATTN_BH * ATTN_S * ATTN_D)

static __device__ __forceinline__ float fast_exp2(float x) {
#if __has_builtin(__builtin_amdgcn_exp2f)
  return __builtin_amdgcn_exp2f(x);
#else
  return exp2f(x);
#endif
}

// async global->LDS, 16B/lane; LDS dest = wave-uniform base + lane*16 (HW rule)
#define GLOAD16(gp, lp)                                                    \
  __builtin_amdgcn_global_load_lds(                                        \
      (__attribute__((address_space(1))) void*)(gp),                       \
      (__attribute__((address_space(3))) void*)(lp), 16, 0, 0)

// ============================================================================
// Pre-convert: Qh = fp16(Q*0.125); Kh = fp16(K) with 16B-chunk XOR swizzle
// (chunk_phys = chunk ^ (row&7)) so linear global_load_lds lands pre-swizzled
// and ds_read_b128 column-slices are bank-conflict-free; Vt = fp16(V^T),
// tiled [bh][kt][d][64] with the same chunk swizzle on the k dimension.
// ============================================================================
__global__ __launch_bounds__(256)
void preconvert_kernel(const float* __restrict__ Q, const float* __restrict__ K,
                       const float* __restrict__ V, _Float16* __restrict__ ws)
{
  if (blockIdx.x < 4096) {
    const int gid = blockIdx.x * 256 + threadIdx.x;   // 0 .. 1048575
    const int isK = gid >> 19;                        // 0: Q, 1: K
    const int id  = gid & 0x7FFFF;                    // 0 .. 524287
    const int row = id >> 3;                          // 0 .. 65535 (bh*2048 + r)
    const int c   = id & 7;                           // logical 8-half chunk
    const float* src = (isK ? K : Q) + ((size_t)row << 6) + (c << 3);
    floatx4 f0 = *(const floatx4*)src;
    floatx4 f1 = *(const floatx4*)(src + 4);
    half8 h;
    if (!isK) {
#pragma unroll
      for (int j = 0; j < 4; ++j) {
        h[j]     = (_Float16)(f0[j] * 0.125f);   // exact pow2 prescale (1/sqrt(64))
        h[4 + j] = (_Float16)(f1[j] * 0.125f);
      }
      *(half8*)(ws + ((size_t)row << 6) + (c << 3)) = h;
    } else {
#pragma unroll
      for (int j = 0; j < 4; ++j) { h[j] = (_Float16)f0[j]; h[4 + j] = (_Float16)f1[j]; }
      const int cp = c ^ (row & 7);
      *(half8*)(ws + QH_ELEMS + ((size_t)row << 6) + (cp << 3)) = h;
    }
  } else {
    // V transpose, one block per (bh, kt): 64x64 tile
    const int blk = blockIdx.x - 4096;                // bh*32 + kt
    __shared__ _Float16 sT[64][72];                   // [k][d], padded
    const float* Vb = V + (size_t)blk * 64 * 64;      // == (bh*2048 + kt*64)*64
#pragma unroll
    for (int it = 0; it < 4; ++it) {
      int lin = threadIdx.x + 256 * it;               // 0..1023
      int rr = lin >> 4, c4 = lin & 15;
      floatx4 f = *(const floatx4*)(Vb + (size_t)rr * 64 + c4 * 4);
#pragma unroll
      for (int j = 0; j < 4; ++j) sT[rr][c4 * 4 + j] = (_Float16)f[j];
    }
    __syncthreads();
    _Float16* dst = ws + 2 * QH_ELEMS + (size_t)blk * 64 * 64;  // [d][64] per tile
#pragma unroll
    for (int it = 0; it < 2; ++it) {
      int lin = threadIdx.x + 256 * it;               // 0..511
      int d = lin >> 3, cp = lin & 7;
      int c = cp ^ (d & 7);                           // logical chunk for this phys slot
      half8 h;
#pragma unroll
      for (int j = 0; j < 8; ++j) h[j] = sT[c * 8 + j][d];
      *(half8*)(dst + d * 64 + cp * 8) = h;
    }
  }
}

// ============================================================================
// Main kernel. One block = (bh, 128 q rows), 8 waves, wave w owns q rows
// [q0+16w, q0+16w+16). Transposed-score scheme: S^T = mfma(A=K, B=Q) puts
// lane l15 = q, regs = 4 consecutive k -> per-lane scalar denominator,
// register-direct P stores (float4), tiny fp16 per-wave LDS tile for the
// PV B-operand repack. K/Vt staged with global_load_lds, double-buffered,
// counted vmcnt(4) (the 4 newer in-flight ops are this iter's P stores).
// ============================================================================
__global__ __launch_bounds__(512, 4)
void attn_softmax1_kernel(const _Float16* __restrict__ ws,
                          float* __restrict__ Out, float* __restrict__ P)
{
  __shared__ __attribute__((aligned(16))) _Float16 sK [2][KT * ATTN_D];  // 2x8KB linear
  __shared__ __attribute__((aligned(16))) _Float16 sVt[2][ATTN_D * KT];  // 2x8KB linear
  __shared__ __attribute__((aligned(16))) _Float16 sPTh[NWAVE][16][72];  // per-wave P^T fp16

  const int tid  = threadIdx.x;
  const int w    = tid >> 6;
  const int lane = tid & 63;
  const int quad = lane >> 4;
  const int l15  = lane & 15;
  const int rswz = l15 & 7;                 // row bits driving the chunk swizzle

  const int bh = blockIdx.x >> 4;
  const int q0 = (blockIdx.x & 15) * QT;

  const _Float16* Qh = ws + (size_t)bh * ATTN_S * ATTN_D;
  const _Float16* Kh = ws + QH_ELEMS + (size_t)bh * ATTN_S * ATTN_D;
  const _Float16* Vt = ws + 2 * QH_ELEMS + (size_t)bh * ATTN_S * ATTN_D;
  float* Ob = Out + (size_t)bh * ATTN_S * ATTN_D;
  float* Pb = P + (size_t)bh * (size_t)ATTN_S * ATTN_S;

  // Q fragment (B-operand: lane l15 = q, k-dim = d = ch*32 + quad*8 + j)
  const int qrow = q0 + w * 16 + l15;
  const half8 aq0 = *(const half8*)(Qh + (size_t)qrow * ATTN_D + quad * 8);
  const half8 aq1 = *(const half8*)(Qh + (size_t)qrow * ATTN_D + 32 + quad * 8);

  // staging addresses: wave w loads rows 8w..8w+7 of each tile (1KB slice)
  const _Float16* kg = Kh + w * (8 * ATTN_D) + lane * 8;   // + t*4096
  const _Float16* vg = Vt + w * (8 * KT)     + lane * 8;   // + t*4096
  _Float16* ldsK0 = &sK [0][w * 512];
  _Float16* ldsK1 = &sK [1][w * 512];
  _Float16* ldsV0 = &sVt[0][w * 512];
  _Float16* ldsV1 = &sVt[1][w * 512];

  // ================= PASS A: per-q max + sum of exp =================
  float m4[4], l4[4];
#pragma unroll
  for (int r = 0; r < 4; ++r) { m4[r] = -3.0e38f; l4[r] = 0.0f; }

  GLOAD16(kg, ldsK0);
#pragma unroll 2
  for (int t = 0; t < NT; ++t) {
    asm volatile("s_waitcnt vmcnt(0)" ::: "memory");   // own slice of tile t landed
    __builtin_amdgcn_s_barrier();                      // everyone's slice landed
    if (t + 1 < NT) GLOAD16(kg + (size_t)(t + 1) * (KT * ATTN_D), (t & 1) ? ldsK0 : ldsK1);
    const _Float16* kb = sK[t & 1];
#pragma unroll
    for (int n = 0; n < 4; ++n) {
      half8 k0 = *(const half8*)(kb + (n * 16 + l15) * 64 + ((quad    ) ^ rswz) * 8);
      half8 k1 = *(const half8*)(kb + (n * 16 + l15) * 64 + ((quad + 4) ^ rswz) * 8);
      floatx4 acc = {0.f, 0.f, 0.f, 0.f};
      acc = __builtin_amdgcn_mfma_f32_16x16x32_f16(k0, aq0, acc, 0, 0, 0);
      acc = __builtin_amdgcn_mfma_f32_16x16x32_f16(k1, aq1, acc, 0, 0, 0);
#pragma unroll
      for (int r = 0; r < 4; ++r) {       // acc[r]: k = t*64+n*16+quad*4+r, q = qrow
        float s = acc[r];
        m4[r] = fmaxf(m4[r], s);
        l4[r] += fast_exp2(s * LOG2E);
      }
    }
  }
  float m_ = fmaxf(fmaxf(m4[0], m4[1]), fmaxf(m4[2], m4[3]));
  float l_ = (l4[0] + l4[1]) + (l4[2] + l4[3]);
  // cross-quad reduce: lanes sharing l15 hold partials of the same q row
  m_ = fmaxf(m_, __shfl_xor(m_, 16, 64));
  l_ += __shfl_xor(l_, 16, 64);
  m_ = fmaxf(m_, __shfl_xor(m_, 32, 64));
  l_ += __shfl_xor(l_, 32, 64);
  // denom = e^m + sum exp(s) == e^m * (1 + sum exp(s-m)) (reference semantics)
  const float rinv = 1.0f / (fast_exp2(m_ * LOG2E) + l_);

  // ================= PASS B: recompute s, write P, out += P*V =================
  floatx4 oacc[4];
#pragma unroll
  for (int d = 0; d < 4; ++d) oacc[d] = (floatx4){0.f, 0.f, 0.f, 0.f};

  // prologue loads target sK[0]/sVt[0]; last pass-A compute used sK[1] -> disjoint
  GLOAD16(kg, ldsK0);
  GLOAD16(vg, ldsV0);
#pragma unroll 2
  for (int t = 0; t < NT; ++t) {
    if (t == 0) { asm volatile("s_waitcnt vmcnt(0)" ::: "memory"); }
    else        { asm volatile("s_waitcnt vmcnt(4)" ::: "memory"); }  // 4 = P stores of t-1
    __builtin_amdgcn_s_barrier();
    if (t + 1 < NT) {
      GLOAD16(kg + (size_t)(t + 1) * (KT * ATTN_D), (t & 1) ? ldsK0 : ldsK1);
      GLOAD16(vg + (size_t)(t + 1) * (ATTN_D * KT), (t & 1) ? ldsV0 : ldsV1);
    }
    const _Float16* kb = sK [t & 1];
    const _Float16* vb = sVt[t & 1];
    const int kbase = t * KT;

    // QK^T (transposed): p for 16 k's per n-subtile, P stored straight from regs
#pragma unroll
    for (int n = 0; n < 4; ++n) {
      half8 k0 = *(const half8*)(kb + (n * 16 + l15) * 64 + ((quad    ) ^ rswz) * 8);
      half8 k1 = *(const half8*)(kb + (n * 16 + l15) * 64 + ((quad + 4) ^ rswz) * 8);
      floatx4 acc = {0.f, 0.f, 0.f, 0.f};
      acc = __builtin_amdgcn_mfma_f32_16x16x32_f16(k0, aq0, acc, 0, 0, 0);
      acc = __builtin_amdgcn_mfma_f32_16x16x32_f16(k1, aq1, acc, 0, 0, 0);
      floatx4 pv;
#pragma unroll
      for (int r = 0; r < 4; ++r) pv[r] = fast_exp2(acc[r] * LOG2E) * rinv;
      // 4 consecutive k per lane -> 16B store; per instr: 16 rows x 64B segments
      *(floatx4*)(Pb + (size_t)qrow * ATTN_S + kbase + n * 16 + quad * 4) = pv;
      half4v hp = { (_Float16)pv[0], (_Float16)pv[1], (_Float16)pv[2], (_Float16)pv[3] };
      *(half4v*)&sPTh[w][l15][n * 16 + quad * 4] = hp;   // per-wave buffer, no barrier
    }
    // PV: Out^T[d][q] += Vt-frag (A) x p^T-frag (B); intra-wave LDS dep only
#pragma unroll
    for (int ch = 0; ch < 2; ++ch) {
      half8 bp = *(const half8*)&sPTh[w][l15][ch * 32 + quad * 8];
#pragma unroll
      for (int dt = 0; dt < 4; ++dt) {
        half8 av = *(const half8*)(vb + (dt * 16 + l15) * 64 + ((ch * 4 + quad) ^ rswz) * 8);
        oacc[dt] = __builtin_amdgcn_mfma_f32_16x16x32_f16(av, bp, oacc[dt], 0, 0, 0);
      }
    }
  }

  // epilogue: Out^T C-layout (col q = l15, row d = dt*16+quad*4+r) -> Out[q][d]
#pragma unroll
  for (int dt = 0; dt < 4; ++dt)
#pragma unroll
    for (int r = 0; r < 4; ++r)
      Ob[(size_t)qrow * ATTN_D + dt * 16 + quad * 4 + r] = oacc[dt][r];
}

extern "C" void kernel_launch(void* const* d_in, const int* in_sizes, int n_in,
                              void* d_out, int out_size, void* d_ws, size_t ws_size,
                              hipStream_t stream) {
  (void)in_sizes; (void)n_in; (void)out_size; (void)ws_size;
  const float* Q = (const float*)d_in[0];
  const float* K = (const float*)d_in[1];
  const float* V = (const float*)d_in[2];
  float* Out = (float*)d_out;
  float* P   = Out + (size_t)ATTN_BH * ATTN_S * ATTN_D;   // out first, then p_attn
  _Float16* ws = (_Float16*)d_ws;                          // needs 24 MB

  preconvert_kernel<<<dim3(4096 + 1024), dim3(256), 0, stream>>>(Q, K, V, ws);
  attn_softmax1_kernel<<<dim3(ATTN_BH * (ATTN_S / QT)), dim3(512), 0, stream>>>(ws, Out, P);
}